// Round 2
// baseline (289.588 us; speedup 1.0000x reference)
//
#include <hip/hip_runtime.h>
#include <hip/hip_cooperative_groups.h>
#include <math.h>

namespace cg = cooperative_groups;

#define NB 8
#define NC 256
#define NL 4096
#define NK 65
#define NST 128   // supertiles per batch, 32 l-columns each (2 x 16-tiles)

// Per-block stat slots (sr, si, sq, pad) -- fully overwritten every launch,
// so no zeroing pass and no atomics are needed.
__device__ float4 g_part[NB * NST];
// Fallback-path stats
__device__ float g_stats[NB * 4];

// ---------------------------------------------------------------------------
// Shared conv helpers (register sliding window, direct global loads).
// ---------------------------------------------------------------------------
#define LOAD16(W, off)                                                      \
    {                                                                       \
        const int g0_ = l0 + (off);                                         \
        if (g0_ >= 0 && g0_ + 16 <= NL) {  /* block-uniform branch */       \
            _Pragma("unroll")                                               \
            for (int q = 0; q < 4; ++q) {                                   \
                const float4 v_ = *(const float4*)(xr + g0_ + 4 * q);       \
                W[4*q+0] = v_.x; W[4*q+1] = v_.y;                           \
                W[4*q+2] = v_.z; W[4*q+3] = v_.w;                           \
            }                                                               \
        } else {                                                            \
            _Pragma("unroll")                                               \
            for (int q = 0; q < 16; ++q) {                                  \
                const int g_ = g0_ + q;                                     \
                W[q] = (g_ >= 0 && g_ < NL) ? xr[g_] : 0.0f;                \
            }                                                               \
        }                                                                   \
    }

#define CHUNK16(Lo, Hi, tb)                                                 \
    {                                                                       \
        _Pragma("unroll")                                                   \
        for (int j2 = 0; j2 < 16; ++j2) {                                   \
            const float kr_ = kre[(tb) + j2];   /* uniform -> s_load */     \
            const float ki_ = kim[(tb) + j2];                               \
            _Pragma("unroll")                                               \
            for (int i = 0; i < 16; ++i) {                                  \
                const int wi_ = i + j2;                                     \
                const float xv_ = (wi_ < 16) ? Lo[wi_] : Hi[wi_ - 16];      \
                sr[i] = fmaf(xv_, kr_, sr[i]);                              \
                si[i] = fmaf(xv_, ki_, si[i]);                              \
            }                                                               \
        }                                                                   \
    }

// Conv 65 taps + stats + weight + 256-pt radix-4 FFT for one 16-wide tile.
// On return the weighted, UN-normalized FFT result sits in lbuf4 (last FFT
// stage ends with __syncthreads, so all rows are readable).
__device__ __forceinline__ void conv_fft_tile(
    const float* __restrict__ xr,
    const float* __restrict__ kre, const float* __restrict__ kim,
    float wgr, float wgi, int l0,
    float4* lbuf4, const float* twr, const float* twi,
    float& tsr_a, float& tsi_a, float& tsq_a)
{
    const int t = threadIdx.x;

    float sr[16], si[16];
    #pragma unroll
    for (int i = 0; i < 16; ++i) { sr[i] = 0.0f; si[i] = 0.0f; }

    float A[16], B[16];
    LOAD16(A, -32);
    LOAD16(B, -16);
    CHUNK16(A, B, 0);        // taps  0..15
    LOAD16(A, 0);
    CHUNK16(B, A, 16);       // taps 16..31
    LOAD16(B, 16);
    CHUNK16(A, B, 32);       // taps 32..47
    LOAD16(A, 32);
    CHUNK16(B, A, 48);       // taps 48..63
    {   // tail tap j = 64
        const float kr_ = kre[64];
        const float ki_ = kim[64];
        #pragma unroll
        for (int i = 0; i < 16; ++i) {
            sr[i] = fmaf(A[i], kr_, sr[i]);
            si[i] = fmaf(A[i], ki_, si[i]);
        }
    }

    // stats on y = (sr, -si), PRE-weight
    #pragma unroll
    for (int i = 0; i < 16; ++i) {
        tsr_a += sr[i];
        tsi_a -= si[i];
        tsq_a = fmaf(sr[i], sr[i], tsq_a);
        tsq_a = fmaf(si[i], si[i], tsq_a);
    }

    // Protect any prior readers of lbuf4 (tile-A extraction / twiddle init)
    __syncthreads();
    #pragma unroll
    for (int k = 0; k < 8; ++k) {
        float4 o;
        o.x = sr[2*k]   * wgr + si[2*k]   * wgi;
        o.y = sr[2*k]   * wgi - si[2*k]   * wgr;
        o.z = sr[2*k+1] * wgr + si[2*k+1] * wgi;
        o.w = sr[2*k+1] * wgi - si[2*k+1] * wgr;
        lbuf4[t * 9 + k] = o;
    }
    __syncthreads();

    // 4 radix-4 DIF stages over channels (row stride 9 float4)
    #pragma unroll
    for (int s = 0; s < 4; ++s) {
        const int shift = 2 * s;
        const int q = 64 >> shift;
        #pragma unroll
        for (int it = 0; it < 2; ++it) {
            int task = it * 256 + t;
            int lpp = task & 7;
            int m = task >> 3;
            int j = m & (q - 1);
            int blk = m >> (6 - shift);
            int base2 = blk << (8 - shift);
            int e = j << shift;

            int ca = base2 + j;
            float4 a0 = lbuf4[ca*9 + lpp];
            float4 a1 = lbuf4[(ca + q)*9 + lpp];
            float4 a2 = lbuf4[(ca + 2*q)*9 + lpp];
            float4 a3 = lbuf4[(ca + 3*q)*9 + lpp];

            float w1r = twr[e],   w1i = twi[e];
            float w2r = twr[2*e], w2i = twi[2*e];
            float w3r = twr[3*e], w3i = twi[3*e];

            float4 b0, b1, b2, b3;
            {
                float t0r = a0.x + a2.x, t0i = a0.y + a2.y;
                float t1r = a0.x - a2.x, t1i = a0.y - a2.y;
                float t2r = a1.x + a3.x, t2i = a1.y + a3.y;
                float t3r = a1.x - a3.x, t3i = a1.y - a3.y;
                b0.x = t0r + t2r;       b0.y = t0i + t2i;
                float b2r = t0r - t2r,  b2i = t0i - t2i;
                float b1r = t1r + t3i,  b1i = t1i - t3r;
                float b3r = t1r - t3i,  b3i = t1i + t3r;
                b1.x = b1r*w1r - b1i*w1i;  b1.y = b1r*w1i + b1i*w1r;
                b2.x = b2r*w2r - b2i*w2i;  b2.y = b2r*w2i + b2i*w2r;
                b3.x = b3r*w3r - b3i*w3i;  b3.y = b3r*w3i + b3i*w3r;
            }
            {
                float t0r = a0.z + a2.z, t0i = a0.w + a2.w;
                float t1r = a0.z - a2.z, t1i = a0.w - a2.w;
                float t2r = a1.z + a3.z, t2i = a1.w + a3.w;
                float t3r = a1.z - a3.z, t3i = a1.w - a3.w;
                b0.z = t0r + t2r;       b0.w = t0i + t2i;
                float b2r = t0r - t2r,  b2i = t0i - t2i;
                float b1r = t1r + t3i,  b1i = t1i - t3r;
                float b3r = t1r - t3i,  b3i = t1i + t3r;
                b1.z = b1r*w1r - b1i*w1i;  b1.w = b1r*w1i + b1i*w1r;
                b2.z = b2r*w2r - b2i*w2i;  b2.w = b2r*w2i + b2i*w2r;
                b3.z = b3r*w3r - b3i*w3i;  b3.w = b3r*w3i + b3i*w3r;
            }
            lbuf4[ca*9 + lpp]         = b0;
            lbuf4[(ca + q)*9 + lpp]   = b1;
            lbuf4[(ca + 2*q)*9 + lpp] = b2;
            lbuf4[(ca + 3*q)*9 + lpp] = b3;
        }
        __syncthreads();
    }
}

__device__ __forceinline__ int digitrev_shift(int pp) {
    int k = ((pp & 3) << 6) | (((pp >> 2) & 3) << 4)
          | (((pp >> 4) & 3) << 2) | ((pp >> 6) & 3);
    return k ^ 128;  // fftshift
}

// ---------------------------------------------------------------------------
// Single cooperative kernel: conv+stats+weight+FFT for 2 tiles, grid.sync,
// redundant per-batch stat reduction, normalized store. One launch total.
// Grid = NB*NST = 1024 blocks = exactly 4 blocks/CU co-resident
// (LDS 38.5 KB x 4 = 154 KB <= 160 KB; launch_bounds(256,4) keeps VGPR<=128).
// ---------------------------------------------------------------------------
__global__ __launch_bounds__(256, 4) void fused_all_kernel(
    const float* __restrict__ x,
    const float* __restrict__ kre,
    const float* __restrict__ kim,
    const float* __restrict__ wmag,
    const float* __restrict__ wang,
    float* __restrict__ out,
    int out_size)
{
    __shared__ __align__(16) float4 lbuf4[NC * 9];  // 36 KB FFT workspace
    __shared__ float twr[NC], twi[NC];
    __shared__ float red[12];

    const int t = threadIdx.x;              // channel
    const int b = blockIdx.x & 7;           // batch == XCD
    const int st = blockIdx.x >> 3;         // supertile
    const int l0A = st << 5;
    const int l0B = l0A + 16;

    {
        float ang = (float)t * 0.024543692606170260f;  // 2*pi/256
        float s, c;
        sincosf(ang, &s, &c);
        twr[t] = c; twi[t] = -s;
    }
    float sw, cw;
    sincosf(wang[t], &sw, &cw);
    const float wm = wmag[t];
    const float wgr =  wm * cw;             // weight WITHOUT inv_std
    const float wgi = -wm * sw;

    const float* xr = x + (size_t)b * NC * NL + (size_t)t * NL;  // own row
    const bool interleaved = (out_size >= 2 * NB * NC * NL);

    float tsr = 0.0f, tsi = 0.0f, tsq = 0.0f;

    // ---- tile A ----
    conv_fft_tile(xr, kre, kim, wgr, wgi, l0A, lbuf4, twr, twi, tsr, tsi, tsq);

    float2 va2[8];                          // held real-part pairs (16 regs)
    if (!interleaved) {
        #pragma unroll
        for (int it = 0; it < 8; ++it) {
            int task = it * 256 + t;
            int lpp = task & 7, pp = task >> 3;
            float4 v = lbuf4[pp * 9 + lpp];
            va2[it].x = v.x; va2[it].y = v.z;
        }
    } else {
        // rare layout: store raw now, rescale in place after grid sync
        #pragma unroll
        for (int it = 0; it < 8; ++it) {
            int task = it * 256 + t;
            int lpp = task & 7, pp = task >> 3;
            float4 v = lbuf4[pp * 9 + lpp];
            int cout = digitrev_shift(pp);
            size_t fi = 2 * ((size_t)(b * NC + cout) * NL + l0A) + 4 * lpp;
            if (fi + 4 <= (size_t)out_size) *(float4*)(out + fi) = v;
        }
    }

    // ---- tile B (internal pre-write barrier protects the reads above) ----
    conv_fft_tile(xr, kre, kim, wgr, wgi, l0B, lbuf4, twr, twi, tsr, tsi, tsq);

    // ---- block stats -> dedicated slot ----
    #pragma unroll
    for (int off = 32; off > 0; off >>= 1) {
        tsr += __shfl_down(tsr, off);
        tsi += __shfl_down(tsi, off);
        tsq += __shfl_down(tsq, off);
    }
    const int lane = t & 63, wv = t >> 6;
    if (lane == 0) { red[wv*3+0] = tsr; red[wv*3+1] = tsi; red[wv*3+2] = tsq; }
    __syncthreads();
    if (t == 0) {
        float a0 = 0.0f, a1 = 0.0f, a2 = 0.0f;
        for (int i = 0; i < 4; ++i) { a0 += red[i*3]; a1 += red[i*3+1]; a2 += red[i*3+2]; }
        g_part[b * NST + st] = make_float4(a0, a1, a2, 0.0f);
    }

    cg::this_grid().sync();

    // ---- redundant per-batch reduction (128 slots, L2-hot) ----
    float psr = 0.0f, psi = 0.0f, psq = 0.0f;
    if (t < NST) {
        float4 p = g_part[b * NST + t];
        psr = p.x; psi = p.y; psq = p.z;
    }
    #pragma unroll
    for (int off = 32; off > 0; off >>= 1) {
        psr += __shfl_down(psr, off);
        psi += __shfl_down(psi, off);
        psq += __shfl_down(psq, off);
    }
    if (wv < 2 && lane == 0) { red[wv*3+0] = psr; red[wv*3+1] = psi; red[wv*3+2] = psq; }
    __syncthreads();
    if (t == 0) {
        float a0 = red[0] + red[3], a1 = red[1] + red[4], a2 = red[2] + red[5];
        const float n = (float)(NC * NL);
        float var = (a2 - (a0*a0 + a1*a1)/n) / (n - 1.0f);
        red[0] = rsqrtf(var);
    }
    __syncthreads();
    const float inv = red[0];

    // ---- normalized stores ----
    // tile B from lbuf4 (intact across grid.sync; red[] is separate)
    #pragma unroll
    for (int it = 0; it < 8; ++it) {
        int task = it * 256 + t;
        int lpp = task & 7, pp = task >> 3;
        float4 v = lbuf4[pp * 9 + lpp];
        int cout = digitrev_shift(pp);
        if (interleaved) {
            v.x *= inv; v.y *= inv; v.z *= inv; v.w *= inv;
            size_t fi = 2 * ((size_t)(b * NC + cout) * NL + l0B) + 4 * lpp;
            if (fi + 4 <= (size_t)out_size) *(float4*)(out + fi) = v;
        } else {
            size_t fi = (size_t)(b * NC + cout) * NL + l0B + 2 * lpp;
            if (fi + 2 <= (size_t)out_size) {
                float2 o2; o2.x = v.x * inv; o2.y = v.z * inv;
                *(float2*)(out + fi) = o2;
            }
        }
    }
    // tile A
    if (!interleaved) {
        #pragma unroll
        for (int it = 0; it < 8; ++it) {
            int task = it * 256 + t;
            int lpp = task & 7, pp = task >> 3;
            int cout = digitrev_shift(pp);
            size_t fi = (size_t)(b * NC + cout) * NL + l0A + 2 * lpp;
            if (fi + 2 <= (size_t)out_size) {
                float2 o2; o2.x = va2[it].x * inv; o2.y = va2[it].y * inv;
                *(float2*)(out + fi) = o2;
            }
        }
    } else {
        #pragma unroll
        for (int it = 0; it < 8; ++it) {
            int task = it * 256 + t;
            int lpp = task & 7, pp = task >> 3;
            int cout = digitrev_shift(pp);
            size_t fi = 2 * ((size_t)(b * NC + cout) * NL + l0A) + 4 * lpp;
            if (fi + 4 <= (size_t)out_size) {
                float4 v = *(const float4*)(out + fi);
                v.x *= inv; v.y *= inv; v.z *= inv; v.w *= inv;
                *(float4*)(out + fi) = v;
            }
        }
    }
}

// ===========================================================================
// Fallback path (proven R1 kernels) -- used only if cooperative launch fails.
// ===========================================================================
__global__ void zero_stats_kernel() {
    if (threadIdx.x < NB * 4) g_stats[threadIdx.x] = 0.0f;
}

__global__ __launch_bounds__(256) void fused_conv_fft_kernel(
    const float* __restrict__ x,
    const float* __restrict__ kre,
    const float* __restrict__ kim,
    const float* __restrict__ wmag,
    const float* __restrict__ wang,
    float* __restrict__ out,
    int out_size)
{
    __shared__ __align__(16) float4 lbuf4[NC * 9];
    __shared__ float twr[NC], twi[NC];
    __shared__ float red[12];

    const int t = threadIdx.x;
    const int b = blockIdx.x & 7;
    const int l0 = (blockIdx.x >> 3) << 4;

    {
        float ang = (float)t * 0.024543692606170260f;
        float s, c;
        sincosf(ang, &s, &c);
        twr[t] = c; twi[t] = -s;
    }
    float sw, cw;
    sincosf(wang[t], &sw, &cw);
    const float wm = wmag[t];
    const float wgr =  wm * cw;
    const float wgi = -wm * sw;

    const float* xr = x + (size_t)b * NC * NL + (size_t)t * NL;
    const bool interleaved = (out_size >= 2 * NB * NC * NL);

    float tsr = 0.0f, tsi = 0.0f, tsq = 0.0f;
    conv_fft_tile(xr, kre, kim, wgr, wgi, l0, lbuf4, twr, twi, tsr, tsi, tsq);

    #pragma unroll
    for (int it = 0; it < 8; ++it) {
        int task = it * 256 + t;
        int lpp = task & 7, pp = task >> 3;
        float4 v = lbuf4[pp * 9 + lpp];
        int cout = digitrev_shift(pp);
        if (interleaved) {
            size_t fi = 2 * ((size_t)(b * NC + cout) * NL + l0) + 4 * lpp;
            if (fi + 4 <= (size_t)out_size) *(float4*)(out + fi) = v;
        } else {
            size_t fi = (size_t)(b * NC + cout) * NL + l0 + 2 * lpp;
            if (fi + 2 <= (size_t)out_size) {
                float2 o2; o2.x = v.x; o2.y = v.z;
                *(float2*)(out + fi) = o2;
            }
        }
    }

    #pragma unroll
    for (int off = 32; off > 0; off >>= 1) {
        tsr += __shfl_down(tsr, off);
        tsi += __shfl_down(tsi, off);
        tsq += __shfl_down(tsq, off);
    }
    const int lane = t & 63, wv = t >> 6;
    if (lane == 0) { red[wv*3+0] = tsr; red[wv*3+1] = tsi; red[wv*3+2] = tsq; }
    __syncthreads();
    if (t == 0) {
        float a0 = 0.0f, a1 = 0.0f, a2 = 0.0f;
        for (int i = 0; i < 4; ++i) { a0 += red[i*3]; a1 += red[i*3+1]; a2 += red[i*3+2]; }
        atomicAdd(&g_stats[b*4+0], a0);
        atomicAdd(&g_stats[b*4+1], a1);
        atomicAdd(&g_stats[b*4+2], a2);
    }
}

__global__ __launch_bounds__(256) void scale_out_kernel(
    float* __restrict__ out, int out_size)
{
    __shared__ float sinv[NB];
    const int t = threadIdx.x;
    if (t < NB) {
        float sr = g_stats[t*4+0], si = g_stats[t*4+1], sq = g_stats[t*4+2];
        const float n = (float)(NC * NL);
        float var = (sq - (sr*sr + si*si)/n) / (n - 1.0f);
        sinv[t] = rsqrtf(var);
    }
    __syncthreads();

    const int chunk = out_size >> 3;
    const bool p2 = (chunk & (chunk - 1)) == 0;
    const int lb = 31 - __clz(chunk);
    const int n4 = out_size >> 2;
    float4* o4 = (float4*)out;
    for (int i4 = blockIdx.x * blockDim.x + t; i4 < n4;
         i4 += gridDim.x * blockDim.x) {
        int fi = i4 << 2;
        int bidx = p2 ? (fi >> lb) : (fi / chunk);
        float invv = sinv[bidx];
        float4 v = o4[i4];
        v.x *= invv; v.y *= invv; v.z *= invv; v.w *= invv;
        o4[i4] = v;
    }
    int tail0 = n4 << 2;
    int ti = tail0 + blockIdx.x * blockDim.x + t;
    if (ti < out_size) {
        int bidx = p2 ? (ti >> lb) : (ti / chunk);
        out[ti] *= sinv[bidx];
    }
}

extern "C" void kernel_launch(void* const* d_in, const int* in_sizes, int n_in,
                              void* d_out, int out_size, void* d_ws, size_t ws_size,
                              hipStream_t stream)
{
    const float* x   = (const float*)d_in[0];
    const float* kre = (const float*)d_in[1];
    const float* kim = (const float*)d_in[2];
    const float* wm  = (const float*)d_in[3];
    const float* wa  = (const float*)d_in[4];
    float* out = (float*)d_out;
    (void)d_ws; (void)ws_size;

    void* args[7] = { (void*)&x, (void*)&kre, (void*)&kim, (void*)&wm,
                      (void*)&wa, (void*)&out, (void*)&out_size };
    hipError_t e = hipLaunchCooperativeKernel(
        (const void*)fused_all_kernel, dim3(NB * NST), dim3(256),
        args, 0, stream);

    if (e != hipSuccess) {
        (void)hipGetLastError();  // clear sticky error, fall back to R1 path
        zero_stats_kernel<<<1, 64, 0, stream>>>();
        fused_conv_fft_kernel<<<NB * (NL / 16), 256, 0, stream>>>(
            x, kre, kim, wm, wa, out, out_size);
        scale_out_kernel<<<2048, 256, 0, stream>>>(out, out_size);
    }
}

// Round 3
// 147.108 us; speedup vs baseline: 1.9685x; 1.9685x over previous
//
#include <hip/hip_runtime.h>
#include <math.h>

#define NB 8
#define NC 256
#define NL 4096
#define NK 65
#define NSL (NL / 16)   // 256 l-tiles per batch

// Per-block stat slots (sr, si, sq, pad) -- fully overwritten every launch,
// so no zeroing pass and no atomics are needed.
__device__ float4 g_part[NB * NSL];

// XOR-swizzled LDS addressing: row-major [NC][8] float4, bank-group
// swizzle q ^ (row&7). Uniform 8-lanes-per-4-bank-group for every FFT
// stage access pattern and the store phase (b128 optimum), with NO pad:
// LDS = exactly 32 KB -> 5 blocks/CU.
__device__ __forceinline__ int lidx(int row, int q) {
    return (row << 3) + (q ^ (row & 7));
}

// ---------------------------------------------------------------------------
// Conv helpers (register sliding window, direct global loads; x rows are
// XCD-L2 resident via b = bid&7 swizzle, each float4 = one 64B line/lane).
// ---------------------------------------------------------------------------
#define LOAD16(W, off)                                                      \
    {                                                                       \
        const int g0_ = l0 + (off);                                         \
        if (g0_ >= 0 && g0_ + 16 <= NL) {  /* block-uniform branch */       \
            _Pragma("unroll")                                               \
            for (int q = 0; q < 4; ++q) {                                   \
                const float4 v_ = *(const float4*)(xr + g0_ + 4 * q);       \
                W[4*q+0] = v_.x; W[4*q+1] = v_.y;                           \
                W[4*q+2] = v_.z; W[4*q+3] = v_.w;                           \
            }                                                               \
        } else {                                                            \
            _Pragma("unroll")                                               \
            for (int q = 0; q < 16; ++q) {                                  \
                const int g_ = g0_ + q;                                     \
                W[q] = (g_ >= 0 && g_ < NL) ? xr[g_] : 0.0f;                \
            }                                                               \
        }                                                                   \
    }

#define CHUNK16(Lo, Hi, tb)                                                 \
    {                                                                       \
        _Pragma("unroll")                                                   \
        for (int j2 = 0; j2 < 16; ++j2) {                                   \
            const float kr_ = kre[(tb) + j2];   /* uniform -> s_load */     \
            const float ki_ = kim[(tb) + j2];                               \
            _Pragma("unroll")                                               \
            for (int i = 0; i < 16; ++i) {                                  \
                const int wi_ = i + j2;                                     \
                const float xv_ = (wi_ < 16) ? Lo[wi_] : Hi[wi_ - 16];      \
                sr[i] = fmaf(xv_, kr_, sr[i]);                              \
                si[i] = fmaf(xv_, ki_, si[i]);                              \
            }                                                               \
        }                                                                   \
    }

__device__ __forceinline__ int digitrev_shift(int pp) {
    int k = ((pp & 3) << 6) | (((pp >> 2) & 3) << 4)
          | (((pp >> 4) & 3) << 2) | ((pp >> 6) & 3);
    return k ^ 128;  // fftshift
}

// ---------------------------------------------------------------------------
// Fused: conv (65 taps, no staging barriers) + pre-weight stats + weight
// (inv_std deferred by linearity) + 256-pt radix-4 FFT over channels +
// fftshift + un-normalized store + per-block stat slot.
// Block = one 16-wide l-tile, thread = channel. LDS exactly 32 KB.
// Twiddles: all stage exponents satisfy e<64 (e = j*4^s, j < 64/4^s), so
// each thread keeps exp(-2*pi*i*lane/256) in 2 VGPRs; w1 via __shfl,
// w2 = w1^2, w3 = w1*w2 (double-angle, exact). No twiddle LDS.
// ---------------------------------------------------------------------------
__global__ __launch_bounds__(256, 5) void fused_conv_fft_kernel(
    const float* __restrict__ x,
    const float* __restrict__ kre,
    const float* __restrict__ kim,
    const float* __restrict__ wmag,
    const float* __restrict__ wang,
    float* __restrict__ out,
    int out_size)
{
    __shared__ __align__(16) float4 lbuf4[NC * 8];  // exactly 32768 B

    const int t = threadIdx.x;              // channel
    const int b = blockIdx.x & 7;           // batch == XCD
    const int st = blockIdx.x >> 3;         // tile index within batch
    const int l0 = st << 4;                 // tile base
    const int lane = t & 63, wv = t >> 6;

    // per-thread twiddle register: exp(-2*pi*i*lane/256)
    float tw64r, tw64i;
    {
        float ang = (float)lane * 0.024543692606170260f;  // 2*pi/256
        float s, c;
        sincosf(ang, &s, &c);
        tw64r = c; tw64i = -s;
    }
    float sw, cw;
    sincosf(wang[t], &sw, &cw);
    const float wm = wmag[t];
    const float wgr =  wm * cw;             // weight WITHOUT inv_std
    const float wgi = -wm * sw;

    const float* xr = x + (size_t)b * NC * NL + (size_t)t * NL;  // own row
    const bool interleaved = (out_size >= 2 * NB * NC * NL);

    float sr[16], si[16];
    #pragma unroll
    for (int i = 0; i < 16; ++i) { sr[i] = 0.0f; si[i] = 0.0f; }

    // ---- conv: 65 taps, register sliding window, no barriers ----
    float A[16], B[16];
    LOAD16(A, -32);
    LOAD16(B, -16);
    CHUNK16(A, B, 0);        // taps  0..15
    LOAD16(A, 0);
    CHUNK16(B, A, 16);       // taps 16..31
    LOAD16(B, 16);
    CHUNK16(A, B, 32);       // taps 32..47
    LOAD16(A, 32);
    CHUNK16(B, A, 48);       // taps 48..63
    {   // tail tap j = 64: words rel [32, 47] == A
        const float kr_ = kre[64];
        const float ki_ = kim[64];
        #pragma unroll
        for (int i = 0; i < 16; ++i) {
            sr[i] = fmaf(A[i], kr_, sr[i]);
            si[i] = fmaf(A[i], ki_, si[i]);
        }
    }

    // ---- stats on y = (sr, -si), PRE-weight (un-normalized) ----
    float tsr = 0.0f, tsi = 0.0f, tsq = 0.0f;
    #pragma unroll
    for (int i = 0; i < 16; ++i) {
        tsr += sr[i];
        tsi -= si[i];
        tsq = fmaf(sr[i], sr[i], tsq);
        tsq = fmaf(si[i], si[i], tsq);
    }

    // ---- weight: y' = y * (wgr + i*wgi) -> own FFT row (first LDS use) ----
    #pragma unroll
    for (int k = 0; k < 8; ++k) {
        float4 o;
        o.x = sr[2*k]   * wgr + si[2*k]   * wgi;
        o.y = sr[2*k]   * wgi - si[2*k]   * wgr;
        o.z = sr[2*k+1] * wgr + si[2*k+1] * wgi;
        o.w = sr[2*k+1] * wgi - si[2*k+1] * wgr;
        lbuf4[lidx(t, k)] = o;
    }
    __syncthreads();

    // ---- 4 radix-4 DIF stages over channels ----
    #pragma unroll
    for (int s = 0; s < 4; ++s) {
        const int shift = 2 * s;
        const int q = 64 >> shift;
        #pragma unroll
        for (int it = 0; it < 2; ++it) {
            int task = it * 256 + t;       // 512 tasks = 64 butterflies x 8 lpairs
            int lpp = task & 7;
            int m = task >> 3;
            int j = m & (q - 1);
            int blk = m >> (6 - shift);
            int base2 = blk << (8 - shift);

            int ca = base2 + j;
            float4 a0 = lbuf4[lidx(ca, lpp)];
            float4 a1 = lbuf4[lidx(ca + q, lpp)];
            float4 a2 = lbuf4[lidx(ca + 2*q, lpp)];
            float4 a3 = lbuf4[lidx(ca + 3*q, lpp)];

            float w1r, w1i;
            if (s < 3) {
                int e = j << shift;        // e < 64 for all stages
                w1r = __shfl(tw64r, e);
                w1i = __shfl(tw64i, e);
            } else {
                w1r = 1.0f; w1i = 0.0f;    // stage 3: e == 0
            }
            float w2r = fmaf(w1r, w1r, -(w1i * w1i));
            float w2i = 2.0f * w1r * w1i;
            float w3r = w2r * w1r - w2i * w1i;
            float w3i = w2r * w1i + w2i * w1r;

            float4 b0, b1, b2, b3;
            {
                float t0r = a0.x + a2.x, t0i = a0.y + a2.y;
                float t1r = a0.x - a2.x, t1i = a0.y - a2.y;
                float t2r = a1.x + a3.x, t2i = a1.y + a3.y;
                float t3r = a1.x - a3.x, t3i = a1.y - a3.y;
                b0.x = t0r + t2r;       b0.y = t0i + t2i;
                float b2r = t0r - t2r,  b2i = t0i - t2i;
                float b1r = t1r + t3i,  b1i = t1i - t3r;
                float b3r = t1r - t3i,  b3i = t1i + t3r;
                b1.x = b1r*w1r - b1i*w1i;  b1.y = b1r*w1i + b1i*w1r;
                b2.x = b2r*w2r - b2i*w2i;  b2.y = b2r*w2i + b2i*w2r;
                b3.x = b3r*w3r - b3i*w3i;  b3.y = b3r*w3i + b3i*w3r;
            }
            {
                float t0r = a0.z + a2.z, t0i = a0.w + a2.w;
                float t1r = a0.z - a2.z, t1i = a0.w - a2.w;
                float t2r = a1.z + a3.z, t2i = a1.w + a3.w;
                float t3r = a1.z - a3.z, t3i = a1.w - a3.w;
                b0.z = t0r + t2r;       b0.w = t0i + t2i;
                float b2r = t0r - t2r,  b2i = t0i - t2i;
                float b1r = t1r + t3i,  b1i = t1i - t3r;
                float b3r = t1r - t3i,  b3i = t1i + t3r;
                b1.z = b1r*w1r - b1i*w1i;  b1.w = b1r*w1i + b1i*w1r;
                b2.z = b2r*w2r - b2i*w2i;  b2.w = b2r*w2i + b2i*w2r;
                b3.z = b3r*w3r - b3i*w3i;  b3.w = b3r*w3i + b3i*w3r;
            }
            lbuf4[lidx(ca, lpp)]         = b0;
            lbuf4[lidx(ca + q, lpp)]     = b1;
            lbuf4[lidx(ca + 2*q, lpp)]   = b2;
            lbuf4[lidx(ca + 3*q, lpp)]   = b3;
        }
        __syncthreads();
    }

    // ---- store (un-normalized): digit-reverse + fftshift ----
    #pragma unroll
    for (int it = 0; it < 8; ++it) {
        int task = it * 256 + t;
        int lpp = task & 7;
        int pp = task >> 3;
        float4 v = lbuf4[lidx(pp, lpp)];
        int cout = digitrev_shift(pp);
        if (interleaved) {
            size_t fi = 2 * ((size_t)(b * NC + cout) * NL + l0) + 4 * lpp;
            if (fi + 4 <= (size_t)out_size) *(float4*)(out + fi) = v;
        } else {
            size_t fi = (size_t)(b * NC + cout) * NL + l0 + 2 * lpp;
            if (fi + 2 <= (size_t)out_size) {
                float2 o2; o2.x = v.x; o2.y = v.z;
                *(float2*)(out + fi) = o2;
            }
        }
    }

    // ---- block stats -> dedicated slot (red[] aliased into lbuf4) ----
    #pragma unroll
    for (int off = 32; off > 0; off >>= 1) {
        tsr += __shfl_down(tsr, off);
        tsi += __shfl_down(tsi, off);
        tsq += __shfl_down(tsq, off);
    }
    __syncthreads();                        // store-phase reads done
    float* redf = (float*)lbuf4;
    if (lane == 0) { redf[wv*3+0] = tsr; redf[wv*3+1] = tsi; redf[wv*3+2] = tsq; }
    __syncthreads();
    if (t == 0) {
        float a0 = 0.0f, a1 = 0.0f, a2 = 0.0f;
        #pragma unroll
        for (int i = 0; i < 4; ++i) { a0 += redf[i*3]; a1 += redf[i*3+1]; a2 += redf[i*3+2]; }
        g_part[b * NSL + st] = make_float4(a0, a1, a2, 0.0f);
    }
}

// ---------------------------------------------------------------------------
// Per-batch inv_std from g_part (each block redundantly reduces its own
// batch's 256 slots -- 4 KB, L2-hot) + contiguous scale of its out range.
// Grid = 2048 blocks; block j -> batch j>>8, range [j*fpb, (j+1)*fpb).
// ---------------------------------------------------------------------------
__global__ __launch_bounds__(256) void scale_out_kernel(
    float* __restrict__ out, int out_size)
{
    __shared__ float sred[13];
    const int t = threadIdx.x;
    const int j = blockIdx.x;               // 0..2047
    const int b = j >> 8;                   // 256 blocks per batch
    const int lane = t & 63, wv = t >> 6;

    // reduce batch b's 256 slots (thread t -> slot t)
    float4 p = g_part[b * NSL + t];
    float psr = p.x, psi = p.y, psq = p.z;
    #pragma unroll
    for (int off = 32; off > 0; off >>= 1) {
        psr += __shfl_down(psr, off);
        psi += __shfl_down(psi, off);
        psq += __shfl_down(psq, off);
    }
    if (lane == 0) { sred[wv*3+0] = psr; sred[wv*3+1] = psi; sred[wv*3+2] = psq; }
    __syncthreads();
    if (t == 0) {
        float a0 = 0.0f, a1 = 0.0f, a2 = 0.0f;
        #pragma unroll
        for (int i = 0; i < 4; ++i) { a0 += sred[i*3]; a1 += sred[i*3+1]; a2 += sred[i*3+2]; }
        const float n = (float)(NC * NL);
        float var = (a2 - (a0*a0 + a1*a1)/n) / (n - 1.0f);
        sred[12] = rsqrtf(var);
    }
    __syncthreads();
    const float inv = sred[12];

    const int fpb = out_size >> 11;         // floats per block
    const int base = j * fpb;
    if ((fpb & 3) == 0 && ((size_t)(out + base) & 15) == 0) {
        float4* o4 = (float4*)(out + base);
        const int n4 = fpb >> 2;
        for (int i = t; i < n4; i += 256) {
            float4 v = o4[i];
            v.x *= inv; v.y *= inv; v.z *= inv; v.w *= inv;
            o4[i] = v;
        }
    } else {
        for (int i = t; i < fpb; i += 256) out[base + i] *= inv;
    }
    // tail (out_size not divisible by 2048): belongs to the last batch
    if (j == 2047) {
        for (int i = (fpb << 11) + t; i < out_size; i += 256) out[i] *= inv;
    }
}

extern "C" void kernel_launch(void* const* d_in, const int* in_sizes, int n_in,
                              void* d_out, int out_size, void* d_ws, size_t ws_size,
                              hipStream_t stream)
{
    const float* x   = (const float*)d_in[0];
    const float* kre = (const float*)d_in[1];
    const float* kim = (const float*)d_in[2];
    const float* wm  = (const float*)d_in[3];
    const float* wa  = (const float*)d_in[4];
    float* out = (float*)d_out;
    (void)d_ws; (void)ws_size;

    fused_conv_fft_kernel<<<NB * NSL, 256, 0, stream>>>(x, kre, kim, wm, wa,
                                                        out, out_size);
    scale_out_kernel<<<2048, 256, 0, stream>>>(out, out_size);
}

// Round 4
// 141.692 us; speedup vs baseline: 2.0438x; 1.0382x over previous
//
#include <hip/hip_runtime.h>
#include <math.h>

#define NB 8
#define NC 256
#define NL 4096
#define NK 65
#define NSL (NL / 16)   // 256 l-tiles per batch

typedef float vf4 __attribute__((ext_vector_type(4)));
typedef float vf2 __attribute__((ext_vector_type(2)));

// Per-block stat slots (sr, si, sq, pad) -- fully overwritten every launch,
// so no zeroing pass and no atomics are needed.
__device__ float4 g_part[NB * NSL];

// XOR-swizzled LDS addressing: row-major [NC][8] float4, bank-group
// swizzle q ^ (row&7). Uniform 8-lanes-per-4-bank-group for every FFT
// stage access pattern and the store phase (b128 optimum), no pad needed.
__device__ __forceinline__ int lidx(int row, int q) {
    return (row << 3) + (q ^ (row & 7));
}

// ---------------------------------------------------------------------------
// Conv helpers (register sliding window, direct global loads; x rows are
// XCD-L2 resident via b = bid&7 swizzle, each float4 = one 64B line/lane).
// ---------------------------------------------------------------------------
#define LOAD16(W, off)                                                      \
    {                                                                       \
        const int g0_ = l0 + (off);                                         \
        if (g0_ >= 0 && g0_ + 16 <= NL) {  /* block-uniform branch */       \
            _Pragma("unroll")                                               \
            for (int q = 0; q < 4; ++q) {                                   \
                const float4 v_ = *(const float4*)(xr + g0_ + 4 * q);       \
                W[4*q+0] = v_.x; W[4*q+1] = v_.y;                           \
                W[4*q+2] = v_.z; W[4*q+3] = v_.w;                           \
            }                                                               \
        } else {                                                            \
            _Pragma("unroll")                                               \
            for (int q = 0; q < 16; ++q) {                                  \
                const int g_ = g0_ + q;                                     \
                W[q] = (g_ >= 0 && g_ < NL) ? xr[g_] : 0.0f;                \
            }                                                               \
        }                                                                   \
    }

#define CHUNK16(Lo, Hi, tb)                                                 \
    {                                                                       \
        _Pragma("unroll")                                                   \
        for (int j2 = 0; j2 < 16; ++j2) {                                   \
            const float kr_ = kre[(tb) + j2];   /* uniform -> s_load */     \
            const float ki_ = kim[(tb) + j2];                               \
            _Pragma("unroll")                                               \
            for (int i = 0; i < 16; ++i) {                                  \
                const int wi_ = i + j2;                                     \
                const float xv_ = (wi_ < 16) ? Lo[wi_] : Hi[wi_ - 16];      \
                sr[i] = fmaf(xv_, kr_, sr[i]);                              \
                si[i] = fmaf(xv_, ki_, si[i]);                              \
            }                                                               \
        }                                                                   \
    }

__device__ __forceinline__ int digitrev_shift(int pp) {
    int k = ((pp & 3) << 6) | (((pp >> 2) & 3) << 4)
          | (((pp >> 4) & 3) << 2) | ((pp >> 6) & 3);
    return k ^ 128;  // fftshift
}

// ---------------------------------------------------------------------------
// Fused: conv (65 taps, 4-buffer deep-prefetch register window) + pre-weight
// stats + weight (inv_std deferred by linearity) + 256-pt radix-4 FFT over
// channels + fftshift + NONTEMPORAL un-normalized store + per-block stat slot.
// LDS padded to 36 KB + launch_bounds(256,4): exactly 4 blocks/CU -- the
// proven low-traffic regime (R3 showed 5/CU overflows the XCD L2 and
// triggers HBM RMW write amplification). out stores bypass L2 (nt) so the
// whole 4 MB XCD L2 serves the x sliding window.
// ---------------------------------------------------------------------------
__global__ __launch_bounds__(256, 4) void fused_conv_fft_kernel(
    const float* __restrict__ x,
    const float* __restrict__ kre,
    const float* __restrict__ kim,
    const float* __restrict__ wmag,
    const float* __restrict__ wang,
    float* __restrict__ out,
    int out_size)
{
    // 36 KB allocated (indexing stays < NC*8): forces <=4 blocks/CU.
    __shared__ __align__(16) float4 lbuf4[NC * 9];

    const int t = threadIdx.x;              // channel
    const int b = blockIdx.x & 7;           // batch == XCD
    const int st = blockIdx.x >> 3;         // tile index within batch
    const int l0 = st << 4;                 // tile base
    const int lane = t & 63, wv = t >> 6;

    const float* xr = x + (size_t)b * NC * NL + (size_t)t * NL;  // own row
    const bool interleaved = (out_size >= 2 * NB * NC * NL);

    float sr[16], si[16];
    #pragma unroll
    for (int i = 0; i < 16; ++i) { sr[i] = 0.0f; si[i] = 0.0f; }

    // ---- conv: 65 taps, 4-buffer prefetched sliding window, no barriers --
    // 16 dwordx4 loads issued before the first FMA; the W0 reload has two
    // full chunks (1024 FMAs) of slack before its consumer.
    float W0[16], W1[16], W2[16], W3[16];
    LOAD16(W0, -32);
    LOAD16(W1, -16);
    LOAD16(W2, 0);
    LOAD16(W3, 16);
    CHUNK16(W0, W1, 0);      // taps  0..15
    LOAD16(W0, 32);          // words [32,48) -> consumed by chunk 48 + tail
    CHUNK16(W1, W2, 16);     // taps 16..31
    CHUNK16(W2, W3, 32);     // taps 32..47
    CHUNK16(W3, W0, 48);     // taps 48..63
    {   // tail tap j = 64: words rel [32, 47] == W0
        const float kr_ = kre[64];
        const float ki_ = kim[64];
        #pragma unroll
        for (int i = 0; i < 16; ++i) {
            sr[i] = fmaf(W0[i], kr_, sr[i]);
            si[i] = fmaf(W0[i], ki_, si[i]);
        }
    }

    // ---- stats on y = (sr, -si), PRE-weight (un-normalized) ----
    float tsr = 0.0f, tsi = 0.0f, tsq = 0.0f;
    #pragma unroll
    for (int i = 0; i < 16; ++i) {
        tsr += sr[i];
        tsi -= si[i];
        tsq = fmaf(sr[i], sr[i], tsq);
        tsq = fmaf(si[i], si[i], tsq);
    }

    // ---- weight & twiddle constants (computed HERE to keep conv-phase
    //      register liveness low) ----
    float sw, cw;
    sincosf(wang[t], &sw, &cw);
    const float wm = wmag[t];
    const float wgr =  wm * cw;             // weight WITHOUT inv_std
    const float wgi = -wm * sw;
    float tw64r, tw64i;                     // exp(-2*pi*i*lane/256)
    {
        float ang = (float)lane * 0.024543692606170260f;  // 2*pi/256
        float s, c;
        sincosf(ang, &s, &c);
        tw64r = c; tw64i = -s;
    }

    // ---- weight: y' = y * (wgr + i*wgi) -> own FFT row (first LDS use) ----
    #pragma unroll
    for (int k = 0; k < 8; ++k) {
        float4 o;
        o.x = sr[2*k]   * wgr + si[2*k]   * wgi;
        o.y = sr[2*k]   * wgi - si[2*k]   * wgr;
        o.z = sr[2*k+1] * wgr + si[2*k+1] * wgi;
        o.w = sr[2*k+1] * wgi - si[2*k+1] * wgr;
        lbuf4[lidx(t, k)] = o;
    }
    __syncthreads();

    // ---- 4 radix-4 DIF stages over channels ----
    // Twiddles: all stage exponents satisfy e<64, so w1 comes from the
    // per-thread tw64 register via __shfl; w2 = w1^2, w3 = w1*w2.
    #pragma unroll
    for (int s = 0; s < 4; ++s) {
        const int shift = 2 * s;
        const int q = 64 >> shift;
        #pragma unroll
        for (int it = 0; it < 2; ++it) {
            int task = it * 256 + t;       // 512 tasks = 64 butterflies x 8 lpairs
            int lpp = task & 7;
            int m = task >> 3;
            int j = m & (q - 1);
            int blk = m >> (6 - shift);
            int base2 = blk << (8 - shift);

            int ca = base2 + j;
            float4 a0 = lbuf4[lidx(ca, lpp)];
            float4 a1 = lbuf4[lidx(ca + q, lpp)];
            float4 a2 = lbuf4[lidx(ca + 2*q, lpp)];
            float4 a3 = lbuf4[lidx(ca + 3*q, lpp)];

            float w1r, w1i;
            if (s < 3) {
                int e = j << shift;        // e < 64 for all stages
                w1r = __shfl(tw64r, e);
                w1i = __shfl(tw64i, e);
            } else {
                w1r = 1.0f; w1i = 0.0f;    // stage 3: e == 0
            }
            float w2r = fmaf(w1r, w1r, -(w1i * w1i));
            float w2i = 2.0f * w1r * w1i;
            float w3r = w2r * w1r - w2i * w1i;
            float w3i = w2r * w1i + w2i * w1r;

            float4 b0, b1, b2, b3;
            {
                float t0r = a0.x + a2.x, t0i = a0.y + a2.y;
                float t1r = a0.x - a2.x, t1i = a0.y - a2.y;
                float t2r = a1.x + a3.x, t2i = a1.y + a3.y;
                float t3r = a1.x - a3.x, t3i = a1.y - a3.y;
                b0.x = t0r + t2r;       b0.y = t0i + t2i;
                float b2r = t0r - t2r,  b2i = t0i - t2i;
                float b1r = t1r + t3i,  b1i = t1i - t3r;
                float b3r = t1r - t3i,  b3i = t1i + t3r;
                b1.x = b1r*w1r - b1i*w1i;  b1.y = b1r*w1i + b1i*w1r;
                b2.x = b2r*w2r - b2i*w2i;  b2.y = b2r*w2i + b2i*w2r;
                b3.x = b3r*w3r - b3i*w3i;  b3.y = b3r*w3i + b3i*w3r;
            }
            {
                float t0r = a0.z + a2.z, t0i = a0.w + a2.w;
                float t1r = a0.z - a2.z, t1i = a0.w - a2.w;
                float t2r = a1.z + a3.z, t2i = a1.w + a3.w;
                float t3r = a1.z - a3.z, t3i = a1.w - a3.w;
                b0.z = t0r + t2r;       b0.w = t0i + t2i;
                float b2r = t0r - t2r,  b2i = t0i - t2i;
                float b1r = t1r + t3i,  b1i = t1i - t3r;
                float b3r = t1r - t3i,  b3i = t1i + t3r;
                b1.z = b1r*w1r - b1i*w1i;  b1.w = b1r*w1i + b1i*w1r;
                b2.z = b2r*w2r - b2i*w2i;  b2.w = b2r*w2i + b2i*w2r;
                b3.z = b3r*w3r - b3i*w3i;  b3.w = b3r*w3i + b3i*w3r;
            }
            lbuf4[lidx(ca, lpp)]         = b0;
            lbuf4[lidx(ca + q, lpp)]     = b1;
            lbuf4[lidx(ca + 2*q, lpp)]   = b2;
            lbuf4[lidx(ca + 3*q, lpp)]   = b3;
        }
        __syncthreads();
    }

    // ---- store (un-normalized): digit-reverse + fftshift, NONTEMPORAL ----
    #pragma unroll
    for (int it = 0; it < 8; ++it) {
        int task = it * 256 + t;
        int lpp = task & 7;
        int pp = task >> 3;
        float4 v = lbuf4[lidx(pp, lpp)];
        int cout = digitrev_shift(pp);
        if (interleaved) {
            size_t fi = 2 * ((size_t)(b * NC + cout) * NL + l0) + 4 * lpp;
            if (fi + 4 <= (size_t)out_size) {
                vf4 o4; o4.x = v.x; o4.y = v.y; o4.z = v.z; o4.w = v.w;
                __builtin_nontemporal_store(o4, (vf4*)(out + fi));
            }
        } else {
            size_t fi = (size_t)(b * NC + cout) * NL + l0 + 2 * lpp;
            if (fi + 2 <= (size_t)out_size) {
                vf2 o2; o2.x = v.x; o2.y = v.z;
                __builtin_nontemporal_store(o2, (vf2*)(out + fi));
            }
        }
    }

    // ---- block stats -> dedicated slot (reduce via LDS alias) ----
    #pragma unroll
    for (int off = 32; off > 0; off >>= 1) {
        tsr += __shfl_down(tsr, off);
        tsi += __shfl_down(tsi, off);
        tsq += __shfl_down(tsq, off);
    }
    __syncthreads();                        // store-phase reads done
    float* redf = (float*)lbuf4;
    if (lane == 0) { redf[wv*3+0] = tsr; redf[wv*3+1] = tsi; redf[wv*3+2] = tsq; }
    __syncthreads();
    if (t == 0) {
        float a0 = 0.0f, a1 = 0.0f, a2 = 0.0f;
        #pragma unroll
        for (int i = 0; i < 4; ++i) { a0 += redf[i*3]; a1 += redf[i*3+1]; a2 += redf[i*3+2]; }
        g_part[b * NSL + st] = make_float4(a0, a1, a2, 0.0f);
    }
}

// ---------------------------------------------------------------------------
// Per-batch inv_std from g_part (each block redundantly reduces its own
// batch's 256 slots -- 4 KB, L2-hot) + contiguous nontemporal scale of its
// out range. XCD-affine: block j -> batch j&7 (same swizzle as fused).
// ---------------------------------------------------------------------------
__global__ __launch_bounds__(256) void scale_out_kernel(
    float* __restrict__ out, int out_size)
{
    __shared__ float sred[13];
    const int t = threadIdx.x;
    const int j = blockIdx.x;               // 0..2047
    const int b = j & 7;                    // batch == XCD
    const int seg = j >> 3;                 // 256 segments per batch
    const int lane = t & 63, wv = t >> 6;

    // reduce batch b's 256 slots (thread t -> slot t)
    float4 p = g_part[b * NSL + t];
    float psr = p.x, psi = p.y, psq = p.z;
    #pragma unroll
    for (int off = 32; off > 0; off >>= 1) {
        psr += __shfl_down(psr, off);
        psi += __shfl_down(psi, off);
        psq += __shfl_down(psq, off);
    }
    if (lane == 0) { sred[wv*3+0] = psr; sred[wv*3+1] = psi; sred[wv*3+2] = psq; }
    __syncthreads();
    if (t == 0) {
        float a0 = 0.0f, a1 = 0.0f, a2 = 0.0f;
        #pragma unroll
        for (int i = 0; i < 4; ++i) { a0 += sred[i*3]; a1 += sred[i*3+1]; a2 += sred[i*3+2]; }
        const float n = (float)(NC * NL);
        float var = (a2 - (a0*a0 + a1*a1)/n) / (n - 1.0f);
        sred[12] = rsqrtf(var);
    }
    __syncthreads();
    const float inv = sred[12];

    const int fpbatch = out_size >> 3;      // floats per batch
    const int fpseg = fpbatch >> 8;         // floats per segment
    const int base = b * fpbatch + seg * fpseg;
    if ((fpseg & 3) == 0 && ((size_t)(out + base) & 15) == 0) {
        const int n4 = fpseg >> 2;
        for (int i = t; i < n4; i += 256) {
            vf4* p4 = (vf4*)(out + base) + i;
            vf4 v = __builtin_nontemporal_load(p4);
            v.x *= inv; v.y *= inv; v.z *= inv; v.w *= inv;
            __builtin_nontemporal_store(v, p4);
        }
    } else {
        for (int i = t; i < fpseg; i += 256) out[base + i] *= inv;
    }
    // tail (out_size not divisible by 2048): belongs to the last batch,
    // and block j==2047 has b==7.
    if (j == 2047) {
        for (int i = ((out_size >> 11) << 11) + t; i < out_size; i += 256)
            out[i] *= inv;
    }
}

extern "C" void kernel_launch(void* const* d_in, const int* in_sizes, int n_in,
                              void* d_out, int out_size, void* d_ws, size_t ws_size,
                              hipStream_t stream)
{
    const float* x   = (const float*)d_in[0];
    const float* kre = (const float*)d_in[1];
    const float* kim = (const float*)d_in[2];
    const float* wm  = (const float*)d_in[3];
    const float* wa  = (const float*)d_in[4];
    float* out = (float*)d_out;
    (void)d_ws; (void)ws_size;

    fused_conv_fft_kernel<<<NB * NSL, 256, 0, stream>>>(x, kre, kim, wm, wa,
                                                        out, out_size);
    scale_out_kernel<<<2048, 256, 0, stream>>>(out, out_size);
}